// Round 4
// baseline (647.473 us; speedup 1.0000x reference)
//
#include <hip/hip_runtime.h>
#include <hip/hip_bf16.h>

// B=8, C=128, N=16384, NH=8, HD=16, D=128
#define N_SEQ 16384
#define EPSF 1e-6f

typedef unsigned short u16;
typedef unsigned int   u32;
typedef __attribute__((ext_vector_type(8))) __bf16 bf16x8;
typedef __attribute__((ext_vector_type(4))) float  f32x4;

union B8 { u32 w[4]; bf16x8 v; };

__device__ __forceinline__ int rfl(int x){ return __builtin_amdgcn_readfirstlane(x); }
__device__ __forceinline__ u16 f2b(float x){
  union { __hip_bfloat16 h; u16 u; } c; c.h = __float2bfloat16(x); return c.u;
}
__device__ __forceinline__ u32 pk2(float a, float b){
  return (u32)f2b(a) | ((u32)f2b(b) << 16);
}
#define MFMA(a,b,c) __builtin_amdgcn_mfma_f32_16x16x32_bf16((a),(b),(c),0,0,0)

// T2 XOR-swizzled LDS indexers (u16 units): linear rows, idx ^= (row&7)<<3 (i.e. byte ^ (row&7)<<4).
// Preserves 16B alignment of 8-elem blocks (f multiple of 8) and 8B alignment of 4-elem blocks.
__device__ __forceinline__ int xidx(int n, int f){ return n*128 + (f ^ ((n & 7) << 3)); } // [64 n][128 f]
__device__ __forceinline__ int kidx(int d, int n){ return d*64  + (n ^ ((d & 7) << 3)); } // [128 d][64 n]

// Pack A-fragments for a 16-row weight slice: out[ks*4+t], k = ks*32 + g*8 + j.
// Lane (g,m) supplies A[m][k] = W[row=base+m][koff + k].
__device__ __forceinline__ void load_wfrag(const float* __restrict__ W, int row, int ldw,
                                           int koff, int g, u32* out){
  #pragma unroll
  for (int ks = 0; ks < 4; ++ks){
    const float* p = W + (size_t)row*ldw + koff + ks*32 + g*8;
    float4 a0 = *reinterpret_cast<const float4*>(p);
    float4 a1 = *reinterpret_cast<const float4*>(p + 4);
    out[ks*4+0] = pk2(a0.x, a0.y);
    out[ks*4+1] = pk2(a0.z, a0.w);
    out[ks*4+2] = pk2(a1.x, a1.y);
    out[ks*4+3] = pk2(a1.z, a1.w);
  }
}

// q[nt] += Wfrag @ X   (X: [n][feat] bf16 LDS, swizzled; K=128; N=64 as 4 ntiles)
__device__ __forceinline__ void gemm16(const u32* wf, const u16* __restrict__ Xl,
                                       int m, int g, f32x4 q[4]){
  #pragma unroll
  for (int ks = 0; ks < 4; ++ks){
    B8 a; a.w[0]=wf[ks*4+0]; a.w[1]=wf[ks*4+1]; a.w[2]=wf[ks*4+2]; a.w[3]=wf[ks*4+3];
    #pragma unroll
    for (int nt = 0; nt < 4; ++nt){
      const bf16x8 bv = *reinterpret_cast<const bf16x8*>(&Xl[xidx(nt*16+m, ks*32 + g*8)]);
      q[nt] = MFMA(a.v, bv, q[nt]);
    }
  }
}

// One attention+Wback stage: T += Wback @ [ sum_s z_s * (qh @ KV_s) ],  qh = relu(Wq@T)+eps.
// Leaves updated T (f32 regs) and refreshed bf16 X tile in LDS. 2 barriers.
template<int NSRC>
__device__ __forceinline__ void stage(u16* Xl, u16* Ul, const u32* wqf,
    const float* __restrict__ Wback, const float* __restrict__ kvf,
    const float* __restrict__ ksf,
    int s1, int s2, int b, int w, int g, int m, int rb, float (&Treg)[4][4]){
  const int sA = ((s1*8 + b)*8 + w);
  const int sB = ((s2*8 + b)*8 + w);
  float4 ksA = *reinterpret_cast<const float4*>(ksf + sA*16 + 4*g);
  float4 ksB = ksA;
  B8 kA, kB;
  #pragma unroll
  for (int t = 0; t < 4; ++t){     // A[m][k] = KV[k][m] for k<16 (K zero-padded via B)
    const float* p = kvf + (size_t)sA*256 + ((g&1)*8 + 2*t)*16 + m;
    kA.w[t] = pk2(p[0], p[16]);
  }
  if (NSRC == 2){
    ksB = *reinterpret_cast<const float4*>(ksf + sB*16 + 4*g);
    #pragma unroll
    for (int t = 0; t < 4; ++t){
      const float* p = kvf + (size_t)sB*256 + ((g&1)*8 + 2*t)*16 + m;
      kB.w[t] = pk2(p[0], p[16]);
    }
  }
  // qh = relu(Wq @ X) + eps  (C/D regs: row rb+4g+r, col nt*16+m)
  f32x4 q[4];
  #pragma unroll
  for (int nt = 0; nt < 4; ++nt) q[nt] = (f32x4){0.f,0.f,0.f,0.f};
  gemm16(wqf, Xl, m, g, q);
  #pragma unroll
  for (int nt = 0; nt < 4; ++nt)
    #pragma unroll
    for (int r = 0; r < 4; ++r) q[nt][r] = fmaxf(q[nt][r], 0.f) + EPSF;
  // z_s(n, h=w) = 1/(qh . Ks_s + eps): partial over own 4 rows, reduce over lane-groups
  float z1[4], z2[4];
  #pragma unroll
  for (int nt = 0; nt < 4; ++nt){
    float p = q[nt][0]*ksA.x + q[nt][1]*ksA.y + q[nt][2]*ksA.z + q[nt][3]*ksA.w;
    p += __shfl_xor(p, 16); p += __shfl_xor(p, 32);
    z1[nt] = 1.0f / (p + EPSF);
  }
  if (NSRC == 2){
    #pragma unroll
    for (int nt = 0; nt < 4; ++nt){
      float p = q[nt][0]*ksB.x + q[nt][1]*ksB.y + q[nt][2]*ksB.z + q[nt][3]*ksB.w;
      p += __shfl_xor(p, 16); p += __shfl_xor(p, 32);
      z2[nt] = 1.0f / (p + EPSF);
    }
  }
  // pack qh (bf16 pairs along rows)
  u32 pq0[4], pq1[4];
  #pragma unroll
  for (int nt = 0; nt < 4; ++nt){
    pq0[nt] = pk2(q[nt][0], q[nt][1]);
    pq1[nt] = pk2(q[nt][2], q[nt][3]);
  }
  // PV: per nt build B[k=d][col] from own wave's qh via shuffles (K=16, pad to 32 with zeros)
  const int sl = (g&1)*32 + m;
  #pragma unroll
  for (int nt = 0; nt < 4; ++nt){
    u32 v0 = (u32)__shfl((int)pq0[nt], sl);
    u32 v1 = (u32)__shfl((int)pq1[nt], sl);
    u32 v2 = (u32)__shfl((int)pq0[nt], sl + 16);
    u32 v3 = (u32)__shfl((int)pq1[nt], sl + 16);
    if (g >= 2){ v0 = v1 = v2 = v3 = 0u; }
    B8 bb; bb.w[0]=v0; bb.w[1]=v1; bb.w[2]=v2; bb.w[3]=v3;
    const f32x4 z4 = (f32x4){0.f,0.f,0.f,0.f};
    f32x4 S1 = MFMA(kA.v, bb.v, z4);
    f32x4 Uv = S1 * z1[nt];
    if (NSRC == 2){
      f32x4 S2 = MFMA(kB.v, bb.v, z4);
      Uv += S2 * z2[nt];
    }
    *reinterpret_cast<uint2*>(&Ul[xidx(nt*16+m, rb + 4*g)]) =
      make_uint2(pk2(Uv[0], Uv[1]), pk2(Uv[2], Uv[3]));
  }
  // prefetch Wback A-frags before the barrier (hides L2 latency)
  u32 wbf[16];
  load_wfrag(Wback, rb + m, 128, 0, g, wbf);
  __syncthreads();
  // T += Wback @ U ; refresh X tile
  f32x4 t4[4];
  #pragma unroll
  for (int nt = 0; nt < 4; ++nt) t4[nt] = (f32x4){0.f,0.f,0.f,0.f};
  gemm16(wbf, Ul, m, g, t4);
  #pragma unroll
  for (int nt = 0; nt < 4; ++nt){
    #pragma unroll
    for (int r = 0; r < 4; ++r) Treg[nt][r] += t4[nt][r];
    *reinterpret_cast<uint2*>(&Xl[xidx(nt*16+m, rb + 4*g)]) =
      make_uint2(pk2(Treg[nt][0], Treg[nt][1]), pk2(Treg[nt][2], Treg[nt][3]));
  }
  __syncthreads();
}

// ---------------- Pass 1: partial KV/Ks per 1024-n chunk (MFMA) -----------------------------------
__global__ __launch_bounds__(512, 6) void k_pass1(const float* __restrict__ t1,
    const float* __restrict__ t2, const float* __restrict__ t3, const float* __restrict__ fs,
    const float* __restrict__ Wk, const float* __restrict__ Wv,
    float* __restrict__ pkv, float* __restrict__ pks){
  __shared__ u16 Xl [64*128];    // 16384 B
  __shared__ u16 khl[128*64];    // 16384 B
  __shared__ u16 vl [128*64];    // 16384 B  -> 49152 B -> 3 blocks/CU
  int bid = blockIdx.x;
  int ch = bid & 15, b = (bid >> 4) & 7, s = bid >> 7;
  int tid = threadIdx.x, lane = tid & 63;
  int w = rfl(tid >> 6), rb = w*16;
  int g = lane >> 4, m = lane & 15;
  const float* src = (s==0)?t1:(s==1)?t2:(s==2)?t3:fs;
  src += (size_t)b*128*N_SEQ + ch*1024;
  u32 wkf[16], wvf[16];
  load_wfrag(Wk, rb + m, 128, 0, g, wkf);
  load_wfrag(Wv, rb + m, 128, 0, g, wvf);
  f32x4 kvacc = (f32x4){0.f,0.f,0.f,0.f};
  float ksump[4] = {0.f,0.f,0.f,0.f};
  #pragma unroll 1
  for (int tile = 0; tile < 16; ++tile){
    const float* sp = src + tile*64;
    #pragma unroll
    for (int rr = 0; rr < 8; ++rr){        // coalesced along n; packed u32 LDS writes
      int c = w*16 + rr*2;
      float f0 = sp[(size_t)c*N_SEQ + lane];
      float f1 = sp[(size_t)(c+1)*N_SEQ + lane];
      *reinterpret_cast<u32*>(&Xl[xidx(lane, c)]) = pk2(f0, f1);
    }
    __syncthreads();
    f32x4 kh[4], vv[4];
    #pragma unroll
    for (int nt = 0; nt < 4; ++nt){ kh[nt] = (f32x4){0.f,0.f,0.f,0.f}; vv[nt] = kh[nt]; }
    gemm16(wkf, Xl, m, g, kh);
    gemm16(wvf, Xl, m, g, vv);
    #pragma unroll
    for (int nt = 0; nt < 4; ++nt)
      #pragma unroll
      for (int r = 0; r < 4; ++r){
        float x = fmaxf(kh[nt][r], 0.f) + EPSF;   // kh = relu(.)+eps
        ksump[r] += x;
        khl[kidx(rb + 4*g + r, nt*16 + m)] = f2b(x);
        vl [kidx(rb + 4*g + r, nt*16 + m)] = f2b(vv[nt][r]);
      }
    __syncthreads();
    // KV_w += kh_w(16 x 64n) @ v_w^T : A[d][k=n], B[k=n][col=m-feat]
    #pragma unroll
    for (int ks2 = 0; ks2 < 2; ++ks2){
      const bf16x8 av = *reinterpret_cast<const bf16x8*>(&khl[kidx(rb+m, ks2*32 + g*8)]);
      const bf16x8 bv = *reinterpret_cast<const bf16x8*>(&vl [kidx(rb+m, ks2*32 + g*8)]);
      kvacc = MFMA(av, bv, kvacc);
    }
  }
  size_t pb = (((size_t)(ch*4 + s)*8 + b)*8 + w)*256;
  #pragma unroll
  for (int r = 0; r < 4; ++r)
    pkv[pb + (size_t)(4*g + r)*16 + m] = kvacc[r];
  #pragma unroll
  for (int r = 0; r < 4; ++r){
    float v2 = ksump[r];
    v2 += __shfl_xor(v2, 1); v2 += __shfl_xor(v2, 2);
    v2 += __shfl_xor(v2, 4); v2 += __shfl_xor(v2, 8);
    if (m == 0) pks[(((size_t)(ch*4 + s)*8 + b)*8 + w)*16 + 4*g + r] = v2;
  }
}

// ---------------- Reduce partials over the 16 chunks ----------------------------------------------
__global__ void k_reduce(const float* __restrict__ pkv, const float* __restrict__ pks,
                         float* __restrict__ kvf, float* __restrict__ ksf){
  int i = blockIdx.x*256 + threadIdx.x;
  if (i < 65536){
    float a = 0.f;
    #pragma unroll
    for (int ch = 0; ch < 16; ++ch) a += pkv[(size_t)ch*65536 + i];
    kvf[i] = a;
  } else {
    int j = i - 65536;
    float a = 0.f;
    #pragma unroll
    for (int ch = 0; ch < 16; ++ch) a += pks[(size_t)ch*4096 + j];
    ksf[j] = a;
  }
}

// ---------------- Pass 2: fused per-n pipeline, all GEMMs on MFMA ----------------------------------
__global__ __launch_bounds__(512, 8) void k_pass2(const float* __restrict__ t1,
    const float* __restrict__ t2, const float* __restrict__ t3, const float* __restrict__ fs,
    const float* __restrict__ Wq, const float* __restrict__ Wback, const float* __restrict__ Wout,
    const float* __restrict__ kvf, const float* __restrict__ ksf, float* __restrict__ outp){
  __shared__ u16 Xl[64*128];   // 16384 B
  __shared__ u16 Ul[64*128];   // 16384 B -> 32768 B -> 4 blocks/CU (needs VGPR<=64)
  int bid = blockIdx.x;
  int b = bid >> 8, n0 = (bid & 255) * 64;
  int tid = threadIdx.x, lane = tid & 63;
  int w = rfl(tid >> 6), rb = w*16;
  int g = lane >> 4, m = lane & 15;
  u32 wqf[16];
  load_wfrag(Wq, rb + m, 128, 0, g, wqf);
  f32x4 oacc[4];
  #pragma unroll
  for (int nt = 0; nt < 4; ++nt) oacc[nt] = (f32x4){0.f,0.f,0.f,0.f};

  #pragma unroll 1
  for (int i = 0; i < 3; ++i){
    const float* src = (i==0)?t1:(i==1)?t2:t3;
    int s1 = (i==0)?1:0, s2 = (i==2)?1:2;
    float Treg[4][4];
    #pragma unroll
    for (int nt = 0; nt < 4; ++nt){
      #pragma unroll
      for (int r = 0; r < 4; ++r)
        Treg[nt][r] = src[(size_t)(b*128 + rb + 4*g + r)*N_SEQ + n0 + nt*16 + m];
      *reinterpret_cast<uint2*>(&Xl[xidx(nt*16+m, rb + 4*g)]) =
        make_uint2(pk2(Treg[nt][0], Treg[nt][1]), pk2(Treg[nt][2], Treg[nt][3]));
    }
    __syncthreads();
    stage<2>(Xl, Ul, wqf, Wback, kvf, ksf, s1, s2, b, w, g, m, rb, Treg);  // stage A
    stage<1>(Xl, Ul, wqf, Wback, kvf, ksf, 3, 3, b, w, g, m, rb, Treg);    // stage B (fusion kv)
    // acc += Wout[:, i*128 : i*128+128] @ t_if
    u32 wof[16];
    load_wfrag(Wout, rb + m, 384, i*128, g, wof);
    gemm16(wof, Xl, m, g, oacc);
    __syncthreads();   // before next i overwrites Xl
  }
  #pragma unroll
  for (int nt = 0; nt < 4; ++nt)
    #pragma unroll
    for (int r = 0; r < 4; ++r){
      size_t idx = (size_t)(b*128 + rb + 4*g + r)*N_SEQ + n0 + nt*16 + m;
      outp[idx] = oacc[nt][r] + fs[idx];
    }
}

extern "C" void kernel_launch(void* const* d_in, const int* in_sizes, int n_in,
                              void* d_out, int out_size, void* d_ws, size_t ws_size,
                              hipStream_t stream){
  const float* t1 = (const float*)d_in[0];
  const float* t2 = (const float*)d_in[1];
  const float* t3 = (const float*)d_in[2];
  const float* fs = (const float*)d_in[3];
  const float* Wq = (const float*)d_in[4];
  const float* Wk = (const float*)d_in[5];
  const float* Wv = (const float*)d_in[6];
  const float* Wb = (const float*)d_in[7];
  const float* Wo = (const float*)d_in[8];
  float* outp = (float*)d_out;
  float* ws = (float*)d_ws;
  // ws layout (floats): final KV [65536] | final Ks [4096] | partial KV [16*65536] | partial Ks [16*4096]
  float* kvf = ws;
  float* ksf = ws + 65536;
  float* pkv = ws + 69632;
  float* pks = ws + 69632 + 16*65536;

  k_pass1 <<<dim3(512),  dim3(512), 0, stream>>>(t1, t2, t3, fs, Wk, Wv, pkv, pks);
  k_reduce<<<dim3(272),  dim3(256), 0, stream>>>(pkv, pks, kvf, ksf);
  k_pass2 <<<dim3(2048), dim3(512), 0, stream>>>(t1, t2, t3, fs, Wq, Wb, Wo, kvf, ksf, outp);
}

// Round 5
// 308.532 us; speedup vs baseline: 2.0986x; 2.0986x over previous
//
#include <hip/hip_runtime.h>
#include <hip/hip_bf16.h>

// B=8, C=128, N=16384, NH=8, HD=16, D=128
#define N_SEQ 16384
#define EPSF 1e-6f

typedef unsigned short u16;
typedef unsigned int   u32;
typedef __attribute__((ext_vector_type(8))) __bf16 bf16x8;
typedef __attribute__((ext_vector_type(4))) float  f32x4;

union B8 { u32 w[4]; bf16x8 v; };

__device__ __forceinline__ int rfl(int x){ return __builtin_amdgcn_readfirstlane(x); }
__device__ __forceinline__ u16 f2b(float x){
  union { __hip_bfloat16 h; u16 u; } c; c.h = __float2bfloat16(x); return c.u;
}
__device__ __forceinline__ u32 pk2(float a, float b){
  return (u32)f2b(a) | ((u32)f2b(b) << 16);
}
#define MFMA(a,b,c) __builtin_amdgcn_mfma_f32_16x16x32_bf16((a),(b),(c),0,0,0)

// Swizzled LDS indexers (u16 units): linear rows, idx ^= (row&7)<<3.
__device__ __forceinline__ int xidx(int n, int f){ return n*128 + (f ^ ((n & 7) << 3)); } // [64 n][128 f]
__device__ __forceinline__ int kidx(int d, int n){ return d*64  + (n ^ ((d & 7) << 3)); } // [128 d][64 n]

// Pack A-fragments for a 16-row weight slice: out[ks*4+t], k = ks*32 + g*8 + j.
// Lane (g,m) supplies A[m][k] = W[row=base+m][koff + k].
__device__ __forceinline__ void load_wfrag(const float* __restrict__ W, int row, int ldw,
                                           int koff, int g, u32* out){
  #pragma unroll
  for (int ks = 0; ks < 4; ++ks){
    const float* p = W + (size_t)row*ldw + koff + ks*32 + g*8;
    float4 a0 = *reinterpret_cast<const float4*>(p);
    float4 a1 = *reinterpret_cast<const float4*>(p + 4);
    out[ks*4+0] = pk2(a0.x, a0.y);
    out[ks*4+1] = pk2(a0.z, a0.w);
    out[ks*4+2] = pk2(a1.x, a1.y);
    out[ks*4+3] = pk2(a1.z, a1.w);
  }
}

// q[nt] += Wfrag @ X   (X: [n][feat] bf16 LDS, swizzled; K=128; N=64 as 4 ntiles)
__device__ __forceinline__ void gemm16(const u32* wf, const u16* __restrict__ Xl,
                                       int m, int g, f32x4 q[4]){
  #pragma unroll
  for (int ks = 0; ks < 4; ++ks){
    B8 a; a.w[0]=wf[ks*4+0]; a.w[1]=wf[ks*4+1]; a.w[2]=wf[ks*4+2]; a.w[3]=wf[ks*4+3];
    #pragma unroll
    for (int nt = 0; nt < 4; ++nt){
      const bf16x8 bv = *reinterpret_cast<const bf16x8*>(&Xl[xidx(nt*16+m, ks*32 + g*8)]);
      q[nt] = MFMA(a.v, bv, q[nt]);
    }
  }
}

// One attention+Wback stage: T += Wback @ [ sum_s z_s * (qh @ KV_s) ],  qh = relu(Wq@T)+eps.
// wf is a caller-provided scratch fragment buffer (shared across all weight loads to cap
// register pressure). Leaves updated T (f32 regs) and refreshed bf16 X tile in LDS. 2 barriers.
template<int NSRC>
__device__ __forceinline__ void stage(u16* Xl, u16* Ul, u32 (&wf)[16],
    const float* __restrict__ Wq, const float* __restrict__ Wback,
    const float* __restrict__ kvf, const float* __restrict__ ksf,
    int s1, int s2, int b, int w, int g, int m, int rb, float (&Treg)[4][4]){
  const int sA = ((s1*8 + b)*8 + w);
  const int sB = ((s2*8 + b)*8 + w);
  float4 ksA = *reinterpret_cast<const float4*>(ksf + sA*16 + 4*g);
  float4 ksB = ksA;
  B8 kA, kB;
  #pragma unroll
  for (int t = 0; t < 4; ++t){     // A[m][k] = KV[k][m] for k<16 (K zero-padded via B)
    const float* p = kvf + (size_t)sA*256 + ((g&1)*8 + 2*t)*16 + m;
    kA.w[t] = pk2(p[0], p[16]);
  }
  if (NSRC == 2){
    ksB = *reinterpret_cast<const float4*>(ksf + sB*16 + 4*g);
    #pragma unroll
    for (int t = 0; t < 4; ++t){
      const float* p = kvf + (size_t)sB*256 + ((g&1)*8 + 2*t)*16 + m;
      kB.w[t] = pk2(p[0], p[16]);
    }
  }
  // qh = relu(Wq @ X) + eps  (C/D regs: row rb+4g+r, col nt*16+m)
  load_wfrag(Wq, rb + m, 128, 0, g, wf);
  f32x4 q[4];
  #pragma unroll
  for (int nt = 0; nt < 4; ++nt) q[nt] = (f32x4){0.f,0.f,0.f,0.f};
  gemm16(wf, Xl, m, g, q);
  #pragma unroll
  for (int nt = 0; nt < 4; ++nt)
    #pragma unroll
    for (int r = 0; r < 4; ++r) q[nt][r] = fmaxf(q[nt][r], 0.f) + EPSF;
  // z_s(n, h=w) = 1/(qh . Ks_s + eps): partial over own 4 rows, reduce over lane-groups
  float z1[4], z2[4];
  #pragma unroll
  for (int nt = 0; nt < 4; ++nt){
    float p = q[nt][0]*ksA.x + q[nt][1]*ksA.y + q[nt][2]*ksA.z + q[nt][3]*ksA.w;
    p += __shfl_xor(p, 16); p += __shfl_xor(p, 32);
    z1[nt] = 1.0f / (p + EPSF);
  }
  if (NSRC == 2){
    #pragma unroll
    for (int nt = 0; nt < 4; ++nt){
      float p = q[nt][0]*ksB.x + q[nt][1]*ksB.y + q[nt][2]*ksB.z + q[nt][3]*ksB.w;
      p += __shfl_xor(p, 16); p += __shfl_xor(p, 32);
      z2[nt] = 1.0f / (p + EPSF);
    }
  }
  // pack qh (bf16 pairs along rows); q dies here
  u32 pq0[4], pq1[4];
  #pragma unroll
  for (int nt = 0; nt < 4; ++nt){
    pq0[nt] = pk2(q[nt][0], q[nt][1]);
    pq1[nt] = pk2(q[nt][2], q[nt][3]);
  }
  // PV: per nt build B[k=d][col] from own wave's qh via shuffles (K=16, pad to 32 with zeros)
  const int sl = (g&1)*32 + m;
  #pragma unroll
  for (int nt = 0; nt < 4; ++nt){
    u32 v0 = (u32)__shfl((int)pq0[nt], sl);
    u32 v1 = (u32)__shfl((int)pq1[nt], sl);
    u32 v2 = (u32)__shfl((int)pq0[nt], sl + 16);
    u32 v3 = (u32)__shfl((int)pq1[nt], sl + 16);
    if (g >= 2){ v0 = v1 = v2 = v3 = 0u; }
    B8 bb; bb.w[0]=v0; bb.w[1]=v1; bb.w[2]=v2; bb.w[3]=v3;
    const f32x4 z4 = (f32x4){0.f,0.f,0.f,0.f};
    f32x4 S1 = MFMA(kA.v, bb.v, z4);
    f32x4 Uv = S1 * z1[nt];
    if (NSRC == 2){
      f32x4 S2 = MFMA(kB.v, bb.v, z4);
      Uv += S2 * z2[nt];
    }
    *reinterpret_cast<uint2*>(&Ul[xidx(nt*16+m, rb + 4*g)]) =
      make_uint2(pk2(Uv[0], Uv[1]), pk2(Uv[2], Uv[3]));
  }
  // reload wf with Wback A-frags before the barrier (hides L2 latency; reuses wf slots)
  load_wfrag(Wback, rb + m, 128, 0, g, wf);
  __syncthreads();
  // T += Wback @ U ; refresh X tile
  f32x4 t4[4];
  #pragma unroll
  for (int nt = 0; nt < 4; ++nt) t4[nt] = (f32x4){0.f,0.f,0.f,0.f};
  gemm16(wf, Ul, m, g, t4);
  #pragma unroll
  for (int nt = 0; nt < 4; ++nt){
    #pragma unroll
    for (int r = 0; r < 4; ++r) Treg[nt][r] += t4[nt][r];
    *reinterpret_cast<uint2*>(&Xl[xidx(nt*16+m, rb + 4*g)]) =
      make_uint2(pk2(Treg[nt][0], Treg[nt][1]), pk2(Treg[nt][2], Treg[nt][3]));
  }
  __syncthreads();
}

// ---------------- Pass 1: partial KV/Ks per 1024-n chunk (MFMA) -----------------------------------
__global__ __launch_bounds__(512, 4) void k_pass1(const float* __restrict__ t1,
    const float* __restrict__ t2, const float* __restrict__ t3, const float* __restrict__ fs,
    const float* __restrict__ Wk, const float* __restrict__ Wv,
    float* __restrict__ pkv, float* __restrict__ pks){
  __shared__ u16 Xl [64*128];    // 16384 B
  __shared__ u16 khl[128*64];    // 16384 B
  __shared__ u16 vl [128*64];    // 16384 B  -> 49152 B
  int bid = blockIdx.x;
  int ch = bid & 15, b = (bid >> 4) & 7, s = bid >> 7;
  int tid = threadIdx.x, lane = tid & 63;
  int w = rfl(tid >> 6), rb = w*16;
  int g = lane >> 4, m = lane & 15;
  const float* src = (s==0)?t1:(s==1)?t2:(s==2)?t3:fs;
  src += (size_t)b*128*N_SEQ + ch*1024;
  u32 wkf[16], wvf[16];
  load_wfrag(Wk, rb + m, 128, 0, g, wkf);
  load_wfrag(Wv, rb + m, 128, 0, g, wvf);
  f32x4 kvacc = (f32x4){0.f,0.f,0.f,0.f};
  float ksump[4] = {0.f,0.f,0.f,0.f};
  #pragma unroll 1
  for (int tile = 0; tile < 16; ++tile){
    const float* sp = src + tile*64;
    #pragma unroll
    for (int rr = 0; rr < 8; ++rr){        // coalesced along n; packed u32 LDS writes
      int c = w*16 + rr*2;
      float f0 = sp[(size_t)c*N_SEQ + lane];
      float f1 = sp[(size_t)(c+1)*N_SEQ + lane];
      *reinterpret_cast<u32*>(&Xl[xidx(lane, c)]) = pk2(f0, f1);
    }
    __syncthreads();
    f32x4 kh[4], vv[4];
    #pragma unroll
    for (int nt = 0; nt < 4; ++nt){ kh[nt] = (f32x4){0.f,0.f,0.f,0.f}; vv[nt] = kh[nt]; }
    gemm16(wkf, Xl, m, g, kh);
    gemm16(wvf, Xl, m, g, vv);
    #pragma unroll
    for (int nt = 0; nt < 4; ++nt)
      #pragma unroll
      for (int r = 0; r < 4; ++r){
        float x = fmaxf(kh[nt][r], 0.f) + EPSF;   // kh = relu(.)+eps
        ksump[r] += x;
        khl[kidx(rb + 4*g + r, nt*16 + m)] = f2b(x);
        vl [kidx(rb + 4*g + r, nt*16 + m)] = f2b(vv[nt][r]);
      }
    __syncthreads();
    // KV_w += kh_w(16 x 64n) @ v_w^T : A[d][k=n], B[k=n][col=m-feat]
    #pragma unroll
    for (int ks2 = 0; ks2 < 2; ++ks2){
      const bf16x8 av = *reinterpret_cast<const bf16x8*>(&khl[kidx(rb+m, ks2*32 + g*8)]);
      const bf16x8 bv = *reinterpret_cast<const bf16x8*>(&vl [kidx(rb+m, ks2*32 + g*8)]);
      kvacc = MFMA(av, bv, kvacc);
    }
  }
  size_t pb = (((size_t)(ch*4 + s)*8 + b)*8 + w)*256;
  #pragma unroll
  for (int r = 0; r < 4; ++r)
    pkv[pb + (size_t)(4*g + r)*16 + m] = kvacc[r];
  #pragma unroll
  for (int r = 0; r < 4; ++r){
    float v2 = ksump[r];
    v2 += __shfl_xor(v2, 1); v2 += __shfl_xor(v2, 2);
    v2 += __shfl_xor(v2, 4); v2 += __shfl_xor(v2, 8);
    if (m == 0) pks[(((size_t)(ch*4 + s)*8 + b)*8 + w)*16 + 4*g + r] = v2;
  }
}

// ---------------- Reduce partials over the 16 chunks ----------------------------------------------
__global__ void k_reduce(const float* __restrict__ pkv, const float* __restrict__ pks,
                         float* __restrict__ kvf, float* __restrict__ ksf){
  int i = blockIdx.x*256 + threadIdx.x;
  if (i < 65536){
    float a = 0.f;
    #pragma unroll
    for (int ch = 0; ch < 16; ++ch) a += pkv[(size_t)ch*65536 + i];
    kvf[i] = a;
  } else {
    int j = i - 65536;
    float a = 0.f;
    #pragma unroll
    for (int ch = 0; ch < 16; ++ch) a += pks[(size_t)ch*4096 + j];
    ksf[j] = a;
  }
}

// ---------------- Pass 2: fused per-n pipeline, all GEMMs on MFMA ----------------------------------
__global__ __launch_bounds__(512, 4) void k_pass2(const float* __restrict__ t1,
    const float* __restrict__ t2, const float* __restrict__ t3, const float* __restrict__ fs,
    const float* __restrict__ Wq, const float* __restrict__ Wback, const float* __restrict__ Wout,
    const float* __restrict__ kvf, const float* __restrict__ ksf, float* __restrict__ outp){
  __shared__ u16 Xl[64*128];   // 16384 B
  __shared__ u16 Ul[64*128];   // 16384 B -> 32768 B
  int bid = blockIdx.x;
  int b = bid >> 8, n0 = (bid & 255) * 64;
  int tid = threadIdx.x, lane = tid & 63;
  int w = rfl(tid >> 6), rb = w*16;
  int g = lane >> 4, m = lane & 15;
  u32 wf[16];                 // single shared fragment buffer for Wq/Wback/Wout
  f32x4 oacc[4];
  #pragma unroll
  for (int nt = 0; nt < 4; ++nt) oacc[nt] = (f32x4){0.f,0.f,0.f,0.f};

  #pragma unroll 1
  for (int i = 0; i < 3; ++i){
    const float* src = (i==0)?t1:(i==1)?t2:t3;
    int s1 = (i==0)?1:0, s2 = (i==2)?1:2;
    float Treg[4][4];
    #pragma unroll
    for (int nt = 0; nt < 4; ++nt){
      #pragma unroll
      for (int r = 0; r < 4; ++r)
        Treg[nt][r] = src[(size_t)(b*128 + rb + 4*g + r)*N_SEQ + n0 + nt*16 + m];
      *reinterpret_cast<uint2*>(&Xl[xidx(nt*16+m, rb + 4*g)]) =
        make_uint2(pk2(Treg[nt][0], Treg[nt][1]), pk2(Treg[nt][2], Treg[nt][3]));
    }
    __syncthreads();
    stage<2>(Xl, Ul, wf, Wq, Wback, kvf, ksf, s1, s2, b, w, g, m, rb, Treg);  // stage A
    stage<1>(Xl, Ul, wf, Wq, Wback, kvf, ksf, 3, 3, b, w, g, m, rb, Treg);    // stage B
    // acc += Wout[:, i*128 : i*128+128] @ t_if
    load_wfrag(Wout, rb + m, 384, i*128, g, wf);
    gemm16(wf, Xl, m, g, oacc);
    __syncthreads();   // before next i overwrites Xl
  }
  #pragma unroll
  for (int nt = 0; nt < 4; ++nt)
    #pragma unroll
    for (int r = 0; r < 4; ++r){
      size_t idx = (size_t)(b*128 + rb + 4*g + r)*N_SEQ + n0 + nt*16 + m;
      outp[idx] = oacc[nt][r] + fs[idx];
    }
}

extern "C" void kernel_launch(void* const* d_in, const int* in_sizes, int n_in,
                              void* d_out, int out_size, void* d_ws, size_t ws_size,
                              hipStream_t stream){
  const float* t1 = (const float*)d_in[0];
  const float* t2 = (const float*)d_in[1];
  const float* t3 = (const float*)d_in[2];
  const float* fs = (const float*)d_in[3];
  const float* Wq = (const float*)d_in[4];
  const float* Wk = (const float*)d_in[5];
  const float* Wv = (const float*)d_in[6];
  const float* Wb = (const float*)d_in[7];
  const float* Wo = (const float*)d_in[8];
  float* outp = (float*)d_out;
  float* ws = (float*)d_ws;
  // ws layout (floats): final KV [65536] | final Ks [4096] | partial KV [16*65536] | partial Ks [16*4096]
  float* kvf = ws;
  float* ksf = ws + 65536;
  float* pkv = ws + 69632;
  float* pks = ws + 69632 + 16*65536;

  k_pass1 <<<dim3(512),  dim3(512), 0, stream>>>(t1, t2, t3, fs, Wk, Wv, pkv, pks);
  k_reduce<<<dim3(272),  dim3(256), 0, stream>>>(pkv, pks, kvf, ksf);
  k_pass2 <<<dim3(2048), dim3(512), 0, stream>>>(t1, t2, t3, fs, Wq, Wb, Wo, kvf, ksf, outp);
}

// Round 6
// 285.412 us; speedup vs baseline: 2.2686x; 1.0810x over previous
//
#include <hip/hip_runtime.h>
#include <hip/hip_bf16.h>

// B=8, C=128, N=16384, NH=8, HD=16, D=128
#define N_SEQ 16384
#define EPSF 1e-6f

typedef unsigned short u16;
typedef unsigned int   u32;
typedef __attribute__((ext_vector_type(8))) __bf16 bf16x8;
typedef __attribute__((ext_vector_type(4))) float  f32x4;

union B8 { u32 w[4]; bf16x8 v; };

__device__ __forceinline__ int rfl(int x){ return __builtin_amdgcn_readfirstlane(x); }
__device__ __forceinline__ u16 f2b(float x){
  union { __hip_bfloat16 h; u16 u; } c; c.h = __float2bfloat16(x); return c.u;
}
__device__ __forceinline__ u32 pk2(float a, float b){
  return (u32)f2b(a) | ((u32)f2b(b) << 16);
}
__device__ __forceinline__ float bf2f(u16 v){ return __uint_as_float(((u32)v) << 16); }
#define MFMA(a,b,c) __builtin_amdgcn_mfma_f32_16x16x32_bf16((a),(b),(c),0,0,0)

// Swizzled LDS indexers (u16 units): linear rows, idx ^= (row&7)<<3.
__device__ __forceinline__ int xidx(int n, int f){ return n*128 + (f ^ ((n & 7) << 3)); } // [64 n][128 f]
__device__ __forceinline__ int kidx(int d, int n){ return d*64  + (n ^ ((d & 7) << 3)); } // [128 d][64 n]

// Pack A-fragments for a 16-row weight slice: out[ks*4+t], k = ks*32 + g*8 + j.
// Lane (g,m) supplies A[m][k] = W[row=base+m][koff + k].
__device__ __forceinline__ void load_wfrag(const float* __restrict__ W, int row, int ldw,
                                           int koff, int g, u32* out){
  #pragma unroll
  for (int ks = 0; ks < 4; ++ks){
    const float* p = W + (size_t)row*ldw + koff + ks*32 + g*8;
    float4 a0 = *reinterpret_cast<const float4*>(p);
    float4 a1 = *reinterpret_cast<const float4*>(p + 4);
    out[ks*4+0] = pk2(a0.x, a0.y);
    out[ks*4+1] = pk2(a0.z, a0.w);
    out[ks*4+2] = pk2(a1.x, a1.y);
    out[ks*4+3] = pk2(a1.z, a1.w);
  }
}

// q[nt] += Wfrag @ X   (X: [n][feat] bf16 LDS, swizzled; K=128; N=64 as 4 ntiles)
__device__ __forceinline__ void gemm16(const u32* wf, const u16* __restrict__ Xl,
                                       int m, int g, f32x4 q[4]){
  #pragma unroll
  for (int ks = 0; ks < 4; ++ks){
    B8 a; a.w[0]=wf[ks*4+0]; a.w[1]=wf[ks*4+1]; a.w[2]=wf[ks*4+2]; a.w[3]=wf[ks*4+3];
    #pragma unroll
    for (int nt = 0; nt < 4; ++nt){
      const bf16x8 bv = *reinterpret_cast<const bf16x8*>(&Xl[xidx(nt*16+m, ks*32 + g*8)]);
      q[nt] = MFMA(a.v, bv, q[nt]);
    }
  }
}

// One attention+Wback stage: T += Wback @ [ sum_s z_s * (qh @ KV_s) ],  qh = relu(Wq@T)+eps.
// T's master copy lives as bf16 in Xl (each element owned by one thread -> safe RMW).
// wf is a caller-provided scratch fragment buffer shared across all weight loads. 2 barriers.
template<int NSRC>
__device__ __forceinline__ void stage(u16* Xl, u16* Ul, u32 (&wf)[16],
    const float* __restrict__ Wq, const float* __restrict__ Wback,
    const float* __restrict__ kvf, const float* __restrict__ ksf,
    int s1, int s2, int b, int w, int g, int m, int rb){
  const int sA = ((s1*8 + b)*8 + w);
  const int sB = ((s2*8 + b)*8 + w);
  float4 ksA = *reinterpret_cast<const float4*>(ksf + sA*16 + 4*g);
  float4 ksB = ksA;
  B8 kA, kB;
  #pragma unroll
  for (int t = 0; t < 4; ++t){     // A[m][k] = KV[k][m] for k<16 (K zero-padded via B)
    const float* p = kvf + (size_t)sA*256 + ((g&1)*8 + 2*t)*16 + m;
    kA.w[t] = pk2(p[0], p[16]);
  }
  if (NSRC == 2){
    ksB = *reinterpret_cast<const float4*>(ksf + sB*16 + 4*g);
    #pragma unroll
    for (int t = 0; t < 4; ++t){
      const float* p = kvf + (size_t)sB*256 + ((g&1)*8 + 2*t)*16 + m;
      kB.w[t] = pk2(p[0], p[16]);
    }
  }
  // qh = relu(Wq @ X) + eps  (C/D regs: row rb+4g+r, col nt*16+m)
  load_wfrag(Wq, rb + m, 128, 0, g, wf);
  f32x4 q[4];
  #pragma unroll
  for (int nt = 0; nt < 4; ++nt) q[nt] = (f32x4){0.f,0.f,0.f,0.f};
  gemm16(wf, Xl, m, g, q);
  #pragma unroll
  for (int nt = 0; nt < 4; ++nt)
    #pragma unroll
    for (int r = 0; r < 4; ++r) q[nt][r] = fmaxf(q[nt][r], 0.f) + EPSF;
  // z_s(n, h=w) = 1/(qh . Ks_s + eps): partial over own 4 rows, reduce over lane-groups
  float z1[4], z2[4];
  #pragma unroll
  for (int nt = 0; nt < 4; ++nt){
    float p = q[nt][0]*ksA.x + q[nt][1]*ksA.y + q[nt][2]*ksA.z + q[nt][3]*ksA.w;
    p += __shfl_xor(p, 16); p += __shfl_xor(p, 32);
    z1[nt] = 1.0f / (p + EPSF);
  }
  if (NSRC == 2){
    #pragma unroll
    for (int nt = 0; nt < 4; ++nt){
      float p = q[nt][0]*ksB.x + q[nt][1]*ksB.y + q[nt][2]*ksB.z + q[nt][3]*ksB.w;
      p += __shfl_xor(p, 16); p += __shfl_xor(p, 32);
      z2[nt] = 1.0f / (p + EPSF);
    }
  }
  // pack qh (bf16 pairs along rows); q dies here
  u32 pq0[4], pq1[4];
  #pragma unroll
  for (int nt = 0; nt < 4; ++nt){
    pq0[nt] = pk2(q[nt][0], q[nt][1]);
    pq1[nt] = pk2(q[nt][2], q[nt][3]);
  }
  // PV: per nt build B[k=d][col] from own wave's qh via shuffles (K=16, pad to 32 with zeros)
  const int sl = (g&1)*32 + m;
  #pragma unroll
  for (int nt = 0; nt < 4; ++nt){
    u32 v0 = (u32)__shfl((int)pq0[nt], sl);
    u32 v1 = (u32)__shfl((int)pq1[nt], sl);
    u32 v2 = (u32)__shfl((int)pq0[nt], sl + 16);
    u32 v3 = (u32)__shfl((int)pq1[nt], sl + 16);
    if (g >= 2){ v0 = v1 = v2 = v3 = 0u; }
    B8 bb; bb.w[0]=v0; bb.w[1]=v1; bb.w[2]=v2; bb.w[3]=v3;
    const f32x4 z4 = (f32x4){0.f,0.f,0.f,0.f};
    f32x4 S1 = MFMA(kA.v, bb.v, z4);
    f32x4 Uv = S1 * z1[nt];
    if (NSRC == 2){
      f32x4 S2 = MFMA(kB.v, bb.v, z4);
      Uv += S2 * z2[nt];
    }
    *reinterpret_cast<uint2*>(&Ul[xidx(nt*16+m, rb + 4*g)]) =
      make_uint2(pk2(Uv[0], Uv[1]), pk2(Uv[2], Uv[3]));
  }
  // reload wf with Wback A-frags before the barrier (hides L2 latency; reuses wf slots)
  load_wfrag(Wback, rb + m, 128, 0, g, wf);
  __syncthreads();
  // T += Wback @ U  (read old bf16 T from Xl, add f32 delta, repack)
  f32x4 t4[4];
  #pragma unroll
  for (int nt = 0; nt < 4; ++nt) t4[nt] = (f32x4){0.f,0.f,0.f,0.f};
  gemm16(wf, Ul, m, g, t4);
  #pragma unroll
  for (int nt = 0; nt < 4; ++nt){
    uint2* tp = reinterpret_cast<uint2*>(&Xl[xidx(nt*16+m, rb + 4*g)]);
    uint2 old = *tp;
    float o0 = bf2f((u16)(old.x & 0xffffu)) + t4[nt][0];
    float o1 = bf2f((u16)(old.x >> 16))     + t4[nt][1];
    float o2 = bf2f((u16)(old.y & 0xffffu)) + t4[nt][2];
    float o3 = bf2f((u16)(old.y >> 16))     + t4[nt][3];
    *tp = make_uint2(pk2(o0, o1), pk2(o2, o3));
  }
  __syncthreads();
}

// ---------------- Pass 1: partial KV/Ks per 1024-n chunk (MFMA) -----------------------------------
__global__ __launch_bounds__(512, 4) void k_pass1(const float* __restrict__ t1,
    const float* __restrict__ t2, const float* __restrict__ t3, const float* __restrict__ fs,
    const float* __restrict__ Wk, const float* __restrict__ Wv,
    float* __restrict__ pkv, float* __restrict__ pks){
  __shared__ u16 Xl [64*128];    // 16384 B
  __shared__ u16 khl[128*64];    // 16384 B
  __shared__ u16 vl [128*64];    // 16384 B  -> 49152 B
  int bid = blockIdx.x;
  int ch = bid & 15, b = (bid >> 4) & 7, s = bid >> 7;
  int tid = threadIdx.x, lane = tid & 63;
  int w = rfl(tid >> 6), rb = w*16;
  int g = lane >> 4, m = lane & 15;
  const float* src = (s==0)?t1:(s==1)?t2:(s==2)?t3:fs;
  src += (size_t)b*128*N_SEQ + ch*1024;
  u32 wkf[16], wvf[16];
  load_wfrag(Wk, rb + m, 128, 0, g, wkf);
  load_wfrag(Wv, rb + m, 128, 0, g, wvf);
  f32x4 kvacc = (f32x4){0.f,0.f,0.f,0.f};
  float ksump[4] = {0.f,0.f,0.f,0.f};
  #pragma unroll 1
  for (int tile = 0; tile < 16; ++tile){
    const float* sp = src + tile*64;
    #pragma unroll
    for (int rr = 0; rr < 8; ++rr){        // coalesced along n; packed u32 LDS writes
      int c = w*16 + rr*2;
      float f0 = sp[(size_t)c*N_SEQ + lane];
      float f1 = sp[(size_t)(c+1)*N_SEQ + lane];
      *reinterpret_cast<u32*>(&Xl[xidx(lane, c)]) = pk2(f0, f1);
    }
    __syncthreads();
    f32x4 kh[4], vv[4];
    #pragma unroll
    for (int nt = 0; nt < 4; ++nt){ kh[nt] = (f32x4){0.f,0.f,0.f,0.f}; vv[nt] = kh[nt]; }
    gemm16(wkf, Xl, m, g, kh);
    gemm16(wvf, Xl, m, g, vv);
    #pragma unroll
    for (int nt = 0; nt < 4; ++nt)
      #pragma unroll
      for (int r = 0; r < 4; ++r){
        float x = fmaxf(kh[nt][r], 0.f) + EPSF;   // kh = relu(.)+eps
        ksump[r] += x;
        khl[kidx(rb + 4*g + r, nt*16 + m)] = f2b(x);
        vl [kidx(rb + 4*g + r, nt*16 + m)] = f2b(vv[nt][r]);
      }
    __syncthreads();
    // KV_w += kh_w(16 x 64n) @ v_w^T : A[d][k=n], B[k=n][col=m-feat]
    #pragma unroll
    for (int ks2 = 0; ks2 < 2; ++ks2){
      const bf16x8 av = *reinterpret_cast<const bf16x8*>(&khl[kidx(rb+m, ks2*32 + g*8)]);
      const bf16x8 bv = *reinterpret_cast<const bf16x8*>(&vl [kidx(rb+m, ks2*32 + g*8)]);
      kvacc = MFMA(av, bv, kvacc);
    }
  }
  size_t pb = (((size_t)(ch*4 + s)*8 + b)*8 + w)*256;
  #pragma unroll
  for (int r = 0; r < 4; ++r)
    pkv[pb + (size_t)(4*g + r)*16 + m] = kvacc[r];
  #pragma unroll
  for (int r = 0; r < 4; ++r){
    float v2 = ksump[r];
    v2 += __shfl_xor(v2, 1); v2 += __shfl_xor(v2, 2);
    v2 += __shfl_xor(v2, 4); v2 += __shfl_xor(v2, 8);
    if (m == 0) pks[(((size_t)(ch*4 + s)*8 + b)*8 + w)*16 + 4*g + r] = v2;
  }
}

// ---------------- Reduce partials over the 16 chunks ----------------------------------------------
__global__ void k_reduce(const float* __restrict__ pkv, const float* __restrict__ pks,
                         float* __restrict__ kvf, float* __restrict__ ksf){
  int i = blockIdx.x*256 + threadIdx.x;
  if (i < 65536){
    float a = 0.f;
    #pragma unroll
    for (int ch = 0; ch < 16; ++ch) a += pkv[(size_t)ch*65536 + i];
    kvf[i] = a;
  } else {
    int j = i - 65536;
    float a = 0.f;
    #pragma unroll
    for (int ch = 0; ch < 16; ++ch) a += pks[(size_t)ch*4096 + j];
    ksf[j] = a;
  }
}

// ---------------- Pass 2: fused per-n pipeline, all GEMMs on MFMA ----------------------------------
__global__ __launch_bounds__(512, 4) void k_pass2(const float* __restrict__ t1,
    const float* __restrict__ t2, const float* __restrict__ t3, const float* __restrict__ fs,
    const float* __restrict__ Wq, const float* __restrict__ Wback, const float* __restrict__ Wout,
    const float* __restrict__ kvf, const float* __restrict__ ksf, float* __restrict__ outp){
  __shared__ u16 Xl[64*128];   // 16384 B
  __shared__ u16 Ul[64*128];   // 16384 B -> 32768 B
  int bid = blockIdx.x;
  int b = bid >> 8, n0 = (bid & 255) * 64;
  int tid = threadIdx.x, lane = tid & 63;
  int w = rfl(tid >> 6), rb = w*16;
  int g = lane >> 4, m = lane & 15;
  u32 wf[16];                 // single shared fragment buffer for Wq/Wback/Wout
  f32x4 oacc[4];
  #pragma unroll
  for (int nt = 0; nt < 4; ++nt) oacc[nt] = (f32x4){0.f,0.f,0.f,0.f};

  #pragma unroll 1
  for (int i = 0; i < 3; ++i){
    const float* src = (i==0)?t1:(i==1)?t2:t3;
    int s1 = (i==0)?1:0, s2 = (i==2)?1:2;
    #pragma unroll
    for (int nt = 0; nt < 4; ++nt){
      float f0 = src[(size_t)(b*128 + rb + 4*g + 0)*N_SEQ + n0 + nt*16 + m];
      float f1 = src[(size_t)(b*128 + rb + 4*g + 1)*N_SEQ + n0 + nt*16 + m];
      float f2 = src[(size_t)(b*128 + rb + 4*g + 2)*N_SEQ + n0 + nt*16 + m];
      float f3 = src[(size_t)(b*128 + rb + 4*g + 3)*N_SEQ + n0 + nt*16 + m];
      *reinterpret_cast<uint2*>(&Xl[xidx(nt*16+m, rb + 4*g)]) =
        make_uint2(pk2(f0, f1), pk2(f2, f3));
    }
    __syncthreads();
    stage<2>(Xl, Ul, wf, Wq, Wback, kvf, ksf, s1, s2, b, w, g, m, rb);  // stage A
    stage<1>(Xl, Ul, wf, Wq, Wback, kvf, ksf, 3, 3, b, w, g, m, rb);    // stage B
    // acc += Wout[:, i*128 : i*128+128] @ t_if
    load_wfrag(Wout, rb + m, 384, i*128, g, wf);
    gemm16(wf, Xl, m, g, oacc);
    __syncthreads();   // before next i overwrites Xl
  }
  #pragma unroll
  for (int nt = 0; nt < 4; ++nt)
    #pragma unroll
    for (int r = 0; r < 4; ++r){
      size_t idx = (size_t)(b*128 + rb + 4*g + r)*N_SEQ + n0 + nt*16 + m;
      outp[idx] = oacc[nt][r] + fs[idx];
    }
}

extern "C" void kernel_launch(void* const* d_in, const int* in_sizes, int n_in,
                              void* d_out, int out_size, void* d_ws, size_t ws_size,
                              hipStream_t stream){
  const float* t1 = (const float*)d_in[0];
  const float* t2 = (const float*)d_in[1];
  const float* t3 = (const float*)d_in[2];
  const float* fs = (const float*)d_in[3];
  const float* Wq = (const float*)d_in[4];
  const float* Wk = (const float*)d_in[5];
  const float* Wv = (const float*)d_in[6];
  const float* Wb = (const float*)d_in[7];
  const float* Wo = (const float*)d_in[8];
  float* outp = (float*)d_out;
  float* ws = (float*)d_ws;
  // ws layout (floats): final KV [65536] | final Ks [4096] | partial KV [16*65536] | partial Ks [16*4096]
  float* kvf = ws;
  float* ksf = ws + 65536;
  float* pkv = ws + 69632;
  float* pks = ws + 69632 + 16*65536;

  k_pass1 <<<dim3(512),  dim3(512), 0, stream>>>(t1, t2, t3, fs, Wk, Wv, pkv, pks);
  k_reduce<<<dim3(272),  dim3(256), 0, stream>>>(pkv, pks, kvf, ksf);
  k_pass2 <<<dim3(2048), dim3(512), 0, stream>>>(t1, t2, t3, fs, Wq, Wb, Wo, kvf, ksf, outp);
}

// Round 7
// 222.297 us; speedup vs baseline: 2.9127x; 1.2839x over previous
//
#include <hip/hip_runtime.h>
#include <hip/hip_bf16.h>

// B=8, C=128, N=16384, NH=8, HD=16, D=128
#define N_SEQ 16384
#define EPSF 1e-6f

typedef unsigned short u16;
typedef unsigned int   u32;
typedef __attribute__((ext_vector_type(8))) __bf16 bf16x8;
typedef __attribute__((ext_vector_type(4))) float  f32x4;

union B8 { u32 w[4]; bf16x8 v; };

__device__ __forceinline__ int rfl(int x){ return __builtin_amdgcn_readfirstlane(x); }
__device__ __forceinline__ u16 f2b(float x){
  union { __hip_bfloat16 h; u16 u; } c; c.h = __float2bfloat16(x); return c.u;
}
__device__ __forceinline__ u32 pk2(float a, float b){
  return (u32)f2b(a) | ((u32)f2b(b) << 16);
}
__device__ __forceinline__ float bf2f(u16 v){ return __uint_as_float(((u32)v) << 16); }
#define MFMA(a,b,c) __builtin_amdgcn_mfma_f32_16x16x32_bf16((a),(b),(c),0,0,0)

// Swizzled LDS indexers (u16 units): linear rows, idx ^= (row&7)<<3.
__device__ __forceinline__ int xidx(int n, int f){ return n*128 + (f ^ ((n & 7) << 3)); } // [64 n][128 f]
__device__ __forceinline__ int kidx(int d, int n){ return d*64  + (n ^ ((d & 7) << 3)); } // [128 d][64 n]

// q[nt] += W @ X.  W: prepacked bf16 row-major (ldw u16/row) — A-frags load directly, no cvt.
__device__ __forceinline__ void gemmW(const u16* __restrict__ Wb, int row, int ldw, int koff,
                                      const u16* __restrict__ Xl, int m, int g, f32x4 q[4]){
  #pragma unroll
  for (int ks = 0; ks < 4; ++ks){
    const bf16x8 av = *reinterpret_cast<const bf16x8*>(&Wb[(size_t)row*ldw + koff + ks*32 + g*8]);
    #pragma unroll
    for (int nt = 0; nt < 4; ++nt){
      const bf16x8 bv = *reinterpret_cast<const bf16x8*>(&Xl[xidx(nt*16+m, ks*32 + g*8)]);
      q[nt] = MFMA(av, bv, q[nt]);
    }
  }
}

// One attention+Wback stage: T += Wback @ [ sum_s z_s * (qh @ KV_s) ],  qh = relu(Wq@T)+eps.
// T's master copy lives as bf16 in Xl (each element owned by one thread -> safe RMW). 2 barriers.
template<int NSRC>
__device__ __forceinline__ void stage(u16* Xl, u16* Ul,
    const u16* __restrict__ wqb, const u16* __restrict__ wbb,
    const u32* __restrict__ kvb, const float* __restrict__ ksf,
    int s1, int s2, int b, int w, int g, int m, int rb){
  const int sA = ((s1*8 + b)*8 + w);
  const int sB = ((s2*8 + b)*8 + w);
  float4 ksA = *reinterpret_cast<const float4*>(ksf + sA*16 + 4*g);
  float4 ksB = ksA;
  // KV A-fragment: prepacked pairs, one dwordx4 per source
  B8 kA, kB;
  uint4 ka4 = *reinterpret_cast<const uint4*>(&kvb[sA*128 + (g&1)*64 + m*4]);
  kA.w[0]=ka4.x; kA.w[1]=ka4.y; kA.w[2]=ka4.z; kA.w[3]=ka4.w;
  if (NSRC == 2){
    ksB = *reinterpret_cast<const float4*>(ksf + sB*16 + 4*g);
    uint4 kb4 = *reinterpret_cast<const uint4*>(&kvb[sB*128 + (g&1)*64 + m*4]);
    kB.w[0]=kb4.x; kB.w[1]=kb4.y; kB.w[2]=kb4.z; kB.w[3]=kb4.w;
  }
  // qh = relu(Wq @ X) + eps  (C/D regs: row rb+4g+r, col nt*16+m)
  f32x4 q[4];
  #pragma unroll
  for (int nt = 0; nt < 4; ++nt) q[nt] = (f32x4){0.f,0.f,0.f,0.f};
  gemmW(wqb, rb + m, 128, 0, Xl, m, g, q);
  #pragma unroll
  for (int nt = 0; nt < 4; ++nt)
    #pragma unroll
    for (int r = 0; r < 4; ++r) q[nt][r] = fmaxf(q[nt][r], 0.f) + EPSF;
  // z_s(n, h=w) = 1/(qh . Ks_s + eps): partial over own 4 rows, reduce over lane-groups
  float z1[4], z2[4];
  #pragma unroll
  for (int nt = 0; nt < 4; ++nt){
    float p = q[nt][0]*ksA.x + q[nt][1]*ksA.y + q[nt][2]*ksA.z + q[nt][3]*ksA.w;
    p += __shfl_xor(p, 16); p += __shfl_xor(p, 32);
    z1[nt] = 1.0f / (p + EPSF);
  }
  if (NSRC == 2){
    #pragma unroll
    for (int nt = 0; nt < 4; ++nt){
      float p = q[nt][0]*ksB.x + q[nt][1]*ksB.y + q[nt][2]*ksB.z + q[nt][3]*ksB.w;
      p += __shfl_xor(p, 16); p += __shfl_xor(p, 32);
      z2[nt] = 1.0f / (p + EPSF);
    }
  }
  // pack qh (bf16 pairs along rows); q dies here
  u32 pq0[4], pq1[4];
  #pragma unroll
  for (int nt = 0; nt < 4; ++nt){
    pq0[nt] = pk2(q[nt][0], q[nt][1]);
    pq1[nt] = pk2(q[nt][2], q[nt][3]);
  }
  // PV: per nt build B[k=d][col] from own wave's qh via shuffles (K=16, pad to 32 with zeros)
  const int sl = (g&1)*32 + m;
  #pragma unroll
  for (int nt = 0; nt < 4; ++nt){
    u32 v0 = (u32)__shfl((int)pq0[nt], sl);
    u32 v1 = (u32)__shfl((int)pq1[nt], sl);
    u32 v2 = (u32)__shfl((int)pq0[nt], sl + 16);
    u32 v3 = (u32)__shfl((int)pq1[nt], sl + 16);
    if (g >= 2){ v0 = v1 = v2 = v3 = 0u; }
    B8 bb; bb.w[0]=v0; bb.w[1]=v1; bb.w[2]=v2; bb.w[3]=v3;
    const f32x4 z4 = (f32x4){0.f,0.f,0.f,0.f};
    f32x4 S1 = MFMA(kA.v, bb.v, z4);
    f32x4 Uv = S1 * z1[nt];
    if (NSRC == 2){
      f32x4 S2 = MFMA(kB.v, bb.v, z4);
      Uv += S2 * z2[nt];
    }
    *reinterpret_cast<uint2*>(&Ul[xidx(nt*16+m, rb + 4*g)]) =
      make_uint2(pk2(Uv[0], Uv[1]), pk2(Uv[2], Uv[3]));
  }
  __syncthreads();
  // T += Wback @ U  (read old bf16 T from Xl, add f32 delta, repack)
  f32x4 t4[4];
  #pragma unroll
  for (int nt = 0; nt < 4; ++nt) t4[nt] = (f32x4){0.f,0.f,0.f,0.f};
  gemmW(wbb, rb + m, 128, 0, Ul, m, g, t4);
  #pragma unroll
  for (int nt = 0; nt < 4; ++nt){
    uint2* tp = reinterpret_cast<uint2*>(&Xl[xidx(nt*16+m, rb + 4*g)]);
    uint2 old = *tp;
    float o0 = bf2f((u16)(old.x & 0xffffu)) + t4[nt][0];
    float o1 = bf2f((u16)(old.x >> 16))     + t4[nt][1];
    float o2 = bf2f((u16)(old.y & 0xffffu)) + t4[nt][2];
    float o3 = bf2f((u16)(old.y >> 16))     + t4[nt][3];
    *tp = make_uint2(pk2(o0, o1), pk2(o2, o3));
  }
  __syncthreads();
}

// ---------------- Prepack: all weights -> bf16 row-major (MFMA-ready) ------------------------------
__global__ void k_prepack(const float* __restrict__ Wq, const float* __restrict__ Wk,
                          const float* __restrict__ Wv, const float* __restrict__ Wb,
                          const float* __restrict__ Wo,
                          u16* __restrict__ wqb, u16* __restrict__ wkb, u16* __restrict__ wvb,
                          u16* __restrict__ wbb, u16* __restrict__ wob){
  int i = blockIdx.x*256 + threadIdx.x;     // grid 448*256 = 114688
  if      (i < 16384) wqb[i]         = f2b(Wq[i]);
  else if (i < 32768) wkb[i - 16384] = f2b(Wk[i - 16384]);
  else if (i < 49152) wvb[i - 32768] = f2b(Wv[i - 32768]);
  else if (i < 65536) wbb[i - 49152] = f2b(Wb[i - 49152]);
  else                wob[i - 65536] = f2b(Wo[i - 65536]);
}

// ---------------- Pass 1: partial KV/Ks per 1024-n chunk (MFMA) -----------------------------------
__global__ __launch_bounds__(512, 4) void k_pass1(const float* __restrict__ t1,
    const float* __restrict__ t2, const float* __restrict__ t3, const float* __restrict__ fs,
    const u16* __restrict__ wkb, const u16* __restrict__ wvb,
    float* __restrict__ pkv, float* __restrict__ pks){
  __shared__ u16 Xl [64*128];    // 16384 B
  __shared__ u16 khl[128*64];    // 16384 B
  __shared__ u16 vl [128*64];    // 16384 B  -> 49152 B
  int bid = blockIdx.x;
  int ch = bid & 15, b = (bid >> 4) & 7, s = bid >> 7;
  int tid = threadIdx.x, lane = tid & 63;
  int w = rfl(tid >> 6), rb = w*16;
  int g = lane >> 4, m = lane & 15;
  const float* src = (s==0)?t1:(s==1)?t2:(s==2)?t3:fs;
  src += (size_t)b*128*N_SEQ + ch*1024;
  f32x4 kvacc = (f32x4){0.f,0.f,0.f,0.f};
  float ksump[4] = {0.f,0.f,0.f,0.f};
  #pragma unroll 1
  for (int tile = 0; tile < 16; ++tile){
    const float* sp = src + tile*64;
    #pragma unroll
    for (int rr = 0; rr < 8; ++rr){        // coalesced along n; packed u32 LDS writes
      int c = w*16 + rr*2;
      float f0 = sp[(size_t)c*N_SEQ + lane];
      float f1 = sp[(size_t)(c+1)*N_SEQ + lane];
      *reinterpret_cast<u32*>(&Xl[xidx(lane, c)]) = pk2(f0, f1);
    }
    __syncthreads();
    f32x4 kh[4], vv[4];
    #pragma unroll
    for (int nt = 0; nt < 4; ++nt){ kh[nt] = (f32x4){0.f,0.f,0.f,0.f}; vv[nt] = kh[nt]; }
    gemmW(wkb, rb + m, 128, 0, Xl, m, g, kh);
    gemmW(wvb, rb + m, 128, 0, Xl, m, g, vv);
    #pragma unroll
    for (int nt = 0; nt < 4; ++nt)
      #pragma unroll
      for (int r = 0; r < 4; ++r){
        float x = fmaxf(kh[nt][r], 0.f) + EPSF;   // kh = relu(.)+eps
        ksump[r] += x;
        khl[kidx(rb + 4*g + r, nt*16 + m)] = f2b(x);
        vl [kidx(rb + 4*g + r, nt*16 + m)] = f2b(vv[nt][r]);
      }
    __syncthreads();
    // KV_w += kh_w(16 x 64n) @ v_w^T : A[d][k=n], B[k=n][col=m-feat]
    #pragma unroll
    for (int ks2 = 0; ks2 < 2; ++ks2){
      const bf16x8 av = *reinterpret_cast<const bf16x8*>(&khl[kidx(rb+m, ks2*32 + g*8)]);
      const bf16x8 bv = *reinterpret_cast<const bf16x8*>(&vl [kidx(rb+m, ks2*32 + g*8)]);
      kvacc = MFMA(av, bv, kvacc);
    }
  }
  size_t pb = (((size_t)(ch*4 + s)*8 + b)*8 + w)*256;
  #pragma unroll
  for (int r = 0; r < 4; ++r)
    pkv[pb + (size_t)(4*g + r)*16 + m] = kvacc[r];
  #pragma unroll
  for (int r = 0; r < 4; ++r){
    float v2 = ksump[r];
    v2 += __shfl_xor(v2, 1); v2 += __shfl_xor(v2, 2);
    v2 += __shfl_xor(v2, 4); v2 += __shfl_xor(v2, 8);
    if (m == 0) pks[(((size_t)(ch*4 + s)*8 + b)*8 + w)*16 + 4*g + r] = v2;
  }
}

// ---------------- Reduce partials; emit KV as prepacked bf16 A-fragments ---------------------------
__global__ void k_reduce(const float* __restrict__ pkv, const float* __restrict__ pks,
                         u32* __restrict__ kvb, float* __restrict__ ksf){
  int i = blockIdx.x*256 + threadIdx.x;   // grid 144*256 = 36864
  if (i < 32768){
    int sA = i >> 7, r7 = i & 127;
    int gb = r7 >> 6, m = (r7 >> 2) & 15, t = r7 & 3;
    int d = gb*8 + 2*t;
    float a0 = 0.f, a1 = 0.f;
    #pragma unroll
    for (int ch = 0; ch < 16; ++ch){
      a0 += pkv[(size_t)ch*65536 + sA*256 + d*16 + m];
      a1 += pkv[(size_t)ch*65536 + sA*256 + (d+1)*16 + m];
    }
    kvb[i] = pk2(a0, a1);
  } else {
    int j = i - 32768;   // < 4096
    float a = 0.f;
    #pragma unroll
    for (int ch = 0; ch < 16; ++ch) a += pks[(size_t)ch*4096 + j];
    ksf[j] = a;
  }
}

// ---------------- Pass 2: fused per-n pipeline, all GEMMs on MFMA ----------------------------------
__global__ __launch_bounds__(512, 4) void k_pass2(const float* __restrict__ t1,
    const float* __restrict__ t2, const float* __restrict__ t3, const float* __restrict__ fs,
    const u16* __restrict__ wqb, const u16* __restrict__ wbb, const u16* __restrict__ wob,
    const u32* __restrict__ kvb, const float* __restrict__ ksf, float* __restrict__ outp){
  __shared__ u16 Xl[64*128];   // 16384 B
  __shared__ u16 Ul[64*128];   // 16384 B -> 32768 B
  int bid = blockIdx.x;
  int b = bid >> 8, n0 = (bid & 255) * 64;
  int tid = threadIdx.x, lane = tid & 63;
  int w = rfl(tid >> 6), rb = w*16;
  int g = lane >> 4, m = lane & 15;
  f32x4 oacc[4];
  #pragma unroll
  for (int nt = 0; nt < 4; ++nt) oacc[nt] = (f32x4){0.f,0.f,0.f,0.f};

  #pragma unroll 1
  for (int i = 0; i < 3; ++i){
    const float* src = (i==0)?t1:(i==1)?t2:t3;
    int s1 = (i==0)?1:0, s2 = (i==2)?1:2;
    #pragma unroll
    for (int nt = 0; nt < 4; ++nt){
      float f0 = src[(size_t)(b*128 + rb + 4*g + 0)*N_SEQ + n0 + nt*16 + m];
      float f1 = src[(size_t)(b*128 + rb + 4*g + 1)*N_SEQ + n0 + nt*16 + m];
      float f2 = src[(size_t)(b*128 + rb + 4*g + 2)*N_SEQ + n0 + nt*16 + m];
      float f3 = src[(size_t)(b*128 + rb + 4*g + 3)*N_SEQ + n0 + nt*16 + m];
      *reinterpret_cast<uint2*>(&Xl[xidx(nt*16+m, rb + 4*g)]) =
        make_uint2(pk2(f0, f1), pk2(f2, f3));
    }
    __syncthreads();
    stage<2>(Xl, Ul, wqb, wbb, kvb, ksf, s1, s2, b, w, g, m, rb);  // stage A
    stage<1>(Xl, Ul, wqb, wbb, kvb, ksf, 3, 3, b, w, g, m, rb);    // stage B
    // acc += Wout[:, i*128 : i*128+128] @ t_if
    gemmW(wob, rb + m, 384, i*128, Xl, m, g, oacc);
    __syncthreads();   // before next i overwrites Xl
  }
  #pragma unroll
  for (int nt = 0; nt < 4; ++nt)
    #pragma unroll
    for (int r = 0; r < 4; ++r){
      size_t idx = (size_t)(b*128 + rb + 4*g + r)*N_SEQ + n0 + nt*16 + m;
      outp[idx] = oacc[nt][r] + fs[idx];
    }
}

extern "C" void kernel_launch(void* const* d_in, const int* in_sizes, int n_in,
                              void* d_out, int out_size, void* d_ws, size_t ws_size,
                              hipStream_t stream){
  const float* t1 = (const float*)d_in[0];
  const float* t2 = (const float*)d_in[1];
  const float* t3 = (const float*)d_in[2];
  const float* fs = (const float*)d_in[3];
  const float* Wq = (const float*)d_in[4];
  const float* Wk = (const float*)d_in[5];
  const float* Wv = (const float*)d_in[6];
  const float* Wb = (const float*)d_in[7];
  const float* Wo = (const float*)d_in[8];
  float* outp = (float*)d_out;
  float* ws = (float*)d_ws;
  // ws layout (float units):
  //   pkv [16*65536] | pks [16*4096] | ksf [4096] | kvb [32768 u32]
  //   | wqb,wkb,wvb,wbb [4 * 8192] | wob [24576]     (bf16 halves in float-sized slots)
  float* pkv = ws;
  float* pks = ws + 16*65536;
  float* ksf = ws + 16*65536 + 16*4096;
  u32*  kvb  = (u32*)(ksf + 4096);
  u16*  wqb  = (u16*)(kvb + 32768);
  u16*  wkb  = wqb + 16384;
  u16*  wvb  = wkb + 16384;
  u16*  wbb  = wvb + 16384;
  u16*  wob  = wbb + 16384;   // 49152 u16

  k_prepack<<<dim3(448),  dim3(256), 0, stream>>>(Wq, Wk, Wv, Wb, Wo, wqb, wkb, wvb, wbb, wob);
  k_pass1  <<<dim3(512),  dim3(512), 0, stream>>>(t1, t2, t3, fs, wkb, wvb, pkv, pks);
  k_reduce <<<dim3(144),  dim3(256), 0, stream>>>(pkv, pks, kvb, ksf);
  k_pass2  <<<dim3(2048), dim3(512), 0, stream>>>(t1, t2, t3, fs, wqb, wbb, wob, kvb, ksf, outp);
}

// Round 8
// 206.118 us; speedup vs baseline: 3.1413x; 1.0785x over previous
//
#include <hip/hip_runtime.h>
#include <hip/hip_bf16.h>

// B=8, C=128, N=16384, NH=8, HD=16, D=128
#define N_SEQ 16384
#define EPSF 1e-6f

typedef unsigned short u16;
typedef unsigned int   u32;
typedef __attribute__((ext_vector_type(8))) __bf16 bf16x8;
typedef __attribute__((ext_vector_type(4))) float  f32x4;

union B8 { u32 w[4]; bf16x8 v; };

__device__ __forceinline__ int rfl(int x){ return __builtin_amdgcn_readfirstlane(x); }
__device__ __forceinline__ u16 f2b(float x){
  union { __hip_bfloat16 h; u16 u; } c; c.h = __float2bfloat16(x); return c.u;
}
__device__ __forceinline__ u32 pk2(float a, float b){
  return (u32)f2b(a) | ((u32)f2b(b) << 16);
}
__device__ __forceinline__ float bf2f(u16 v){ return __uint_as_float(((u32)v) << 16); }
#define MFMA(a,b,c) __builtin_amdgcn_mfma_f32_16x16x32_bf16((a),(b),(c),0,0,0)

// Swizzled LDS indexers (u16 units): linear rows, idx ^= (row&7)<<3.
__device__ __forceinline__ int xidx(int n, int f){ return n*128 + (f ^ ((n & 7) << 3)); } // [64 n][128 f]
__device__ __forceinline__ int kidx(int d, int n){ return d*64  + (n ^ ((d & 7) << 3)); } // [128 d][64 n]

#define QTS 24   // u16 stride of Qt rows (48B: 16B-aligned for ds_read_b128)

// q[nt] += W @ X.  W: prepacked bf16 row-major (ldw u16/row) — A-frags load directly, no cvt.
__device__ __forceinline__ void gemmW(const u16* __restrict__ Wb, int row, int ldw, int koff,
                                      const u16* __restrict__ Xl, int m, int g, f32x4 q[4]){
  #pragma unroll
  for (int ks = 0; ks < 4; ++ks){
    const bf16x8 av = *reinterpret_cast<const bf16x8*>(&Wb[(size_t)row*ldw + koff + ks*32 + g*8]);
    #pragma unroll
    for (int nt = 0; nt < 4; ++nt){
      const bf16x8 bv = *reinterpret_cast<const bf16x8*>(&Xl[xidx(nt*16+m, ks*32 + g*8)]);
      q[nt] = MFMA(av, bv, q[nt]);
    }
  }
}

// One attention+Wback stage: T += Wback @ [ sum_s z_s * (qh @ KV_s) ],  qh = relu(Wq@T)+eps.
// T's master copy lives as bf16 in Xl (each element owned by one thread -> safe RMW).
// PV B-fragments come from a per-head LDS transpose buffer Qt (within-wave prod/cons, no barrier).
template<int NSRC>
__device__ __forceinline__ void stage(u16* Xl, u16* Ul, u16* Qt,
    const u16* __restrict__ wqb, const u16* __restrict__ wbb,
    const u32* __restrict__ kvb, const float* __restrict__ ksf,
    int s1, int s2, int b, int w, int g, int m, int rb){
  const int sA = ((s1*8 + b)*8 + w);
  const int sB = ((s2*8 + b)*8 + w);
  float4 ksA = *reinterpret_cast<const float4*>(ksf + sA*16 + 4*g);
  float4 ksB = ksA;
  // KV A-fragment: prepacked pairs, one dwordx4 per source
  B8 kA, kB;
  uint4 ka4 = *reinterpret_cast<const uint4*>(&kvb[sA*128 + (g&1)*64 + m*4]);
  kA.w[0]=ka4.x; kA.w[1]=ka4.y; kA.w[2]=ka4.z; kA.w[3]=ka4.w;
  if (NSRC == 2){
    ksB = *reinterpret_cast<const float4*>(ksf + sB*16 + 4*g);
    uint4 kb4 = *reinterpret_cast<const uint4*>(&kvb[sB*128 + (g&1)*64 + m*4]);
    kB.w[0]=kb4.x; kB.w[1]=kb4.y; kB.w[2]=kb4.z; kB.w[3]=kb4.w;
  }
  // qh = relu(Wq @ X) + eps  (C/D regs: row rb+4g+r, col nt*16+m)
  f32x4 q[4];
  #pragma unroll
  for (int nt = 0; nt < 4; ++nt) q[nt] = (f32x4){0.f,0.f,0.f,0.f};
  gemmW(wqb, rb + m, 128, 0, Xl, m, g, q);
  #pragma unroll
  for (int nt = 0; nt < 4; ++nt)
    #pragma unroll
    for (int r = 0; r < 4; ++r) q[nt][r] = fmaxf(q[nt][r], 0.f) + EPSF;
  // z_s(n, h=w) = 1/(qh . Ks_s + eps): partial over own 4 rows, reduce over lane-groups
  float z1[4], z2[4];
  #pragma unroll
  for (int nt = 0; nt < 4; ++nt){
    float p = q[nt][0]*ksA.x + q[nt][1]*ksA.y + q[nt][2]*ksA.z + q[nt][3]*ksA.w;
    p += __shfl_xor(p, 16); p += __shfl_xor(p, 32);
    z1[nt] = 1.0f / (p + EPSF);
  }
  if (NSRC == 2){
    #pragma unroll
    for (int nt = 0; nt < 4; ++nt){
      float p = q[nt][0]*ksB.x + q[nt][1]*ksB.y + q[nt][2]*ksB.z + q[nt][3]*ksB.w;
      p += __shfl_xor(p, 16); p += __shfl_xor(p, 32);
      z2[nt] = 1.0f / (p + EPSF);
    }
  }
  // qh^T into Qt[head][n][d] (bf16, stride QTS): lane owns d=4g..4g+3 at col n=nt*16+m
  u16* qrow = Qt + w*(64*QTS);
  #pragma unroll
  for (int nt = 0; nt < 4; ++nt)
    *reinterpret_cast<uint2*>(&qrow[(nt*16+m)*QTS + 4*g]) =
      make_uint2(pk2(q[nt][0], q[nt][1]), pk2(q[nt][2], q[nt][3]));
  // PV: B[k=d][col] = Qt[n=nt*16+col][d=g*8+j] (g<2; k>=16 zero-padded)
  #pragma unroll
  for (int nt = 0; nt < 4; ++nt){
    B8 bb;
    if (g < 2) bb.v = *reinterpret_cast<const bf16x8*>(&qrow[(nt*16+m)*QTS + g*8]);
    else { bb.w[0]=0u; bb.w[1]=0u; bb.w[2]=0u; bb.w[3]=0u; }
    const f32x4 z4 = (f32x4){0.f,0.f,0.f,0.f};
    f32x4 S1 = MFMA(kA.v, bb.v, z4);
    f32x4 Uv = S1 * z1[nt];
    if (NSRC == 2){
      f32x4 S2 = MFMA(kB.v, bb.v, z4);
      Uv += S2 * z2[nt];
    }
    *reinterpret_cast<uint2*>(&Ul[xidx(nt*16+m, rb + 4*g)]) =
      make_uint2(pk2(Uv[0], Uv[1]), pk2(Uv[2], Uv[3]));
  }
  // preload old T into the Wback accumulator (MFMA C-in does the add); Xl stable until we store
  f32x4 t4[4];
  #pragma unroll
  for (int nt = 0; nt < 4; ++nt){
    uint2 old = *reinterpret_cast<const uint2*>(&Xl[xidx(nt*16+m, rb + 4*g)]);
    t4[nt][0] = bf2f((u16)(old.x & 0xffffu));
    t4[nt][1] = bf2f((u16)(old.x >> 16));
    t4[nt][2] = bf2f((u16)(old.y & 0xffffu));
    t4[nt][3] = bf2f((u16)(old.y >> 16));
  }
  __syncthreads();
  // T += Wback @ U
  gemmW(wbb, rb + m, 128, 0, Ul, m, g, t4);
  #pragma unroll
  for (int nt = 0; nt < 4; ++nt)
    *reinterpret_cast<uint2*>(&Xl[xidx(nt*16+m, rb + 4*g)]) =
      make_uint2(pk2(t4[nt][0], t4[nt][1]), pk2(t4[nt][2], t4[nt][3]));
  __syncthreads();
}

// ---------------- Prepack: all weights -> bf16 row-major (MFMA-ready) ------------------------------
__global__ void k_prepack(const float* __restrict__ Wq, const float* __restrict__ Wk,
                          const float* __restrict__ Wv, const float* __restrict__ Wb,
                          const float* __restrict__ Wo,
                          u16* __restrict__ wqb, u16* __restrict__ wkb, u16* __restrict__ wvb,
                          u16* __restrict__ wbb, u16* __restrict__ wob){
  int i = blockIdx.x*256 + threadIdx.x;     // grid 448*256 = 114688
  if      (i < 16384) wqb[i]         = f2b(Wq[i]);
  else if (i < 32768) wkb[i - 16384] = f2b(Wk[i - 16384]);
  else if (i < 49152) wvb[i - 32768] = f2b(Wv[i - 32768]);
  else if (i < 65536) wbb[i - 49152] = f2b(Wb[i - 49152]);
  else                wob[i - 65536] = f2b(Wo[i - 65536]);
}

// ---------------- Pass 1: partial KV/Ks per 1024-n chunk (MFMA) -----------------------------------
__global__ __launch_bounds__(512, 4) void k_pass1(const float* __restrict__ t1,
    const float* __restrict__ t2, const float* __restrict__ t3, const float* __restrict__ fs,
    const u16* __restrict__ wkb, const u16* __restrict__ wvb,
    float* __restrict__ pkv, float* __restrict__ pks){
  __shared__ u16 Xl [64*128];    // 16384 B
  __shared__ u16 khl[128*64];    // 16384 B
  __shared__ u16 vl [128*64];    // 16384 B  -> 49152 B
  int bid = blockIdx.x;
  int ch = bid & 15, b = (bid >> 4) & 7, s = bid >> 7;
  int tid = threadIdx.x, lane = tid & 63;
  int w = rfl(tid >> 6), rb = w*16;
  int g = lane >> 4, m = lane & 15;
  const float* src = (s==0)?t1:(s==1)?t2:(s==2)?t3:fs;
  src += (size_t)b*128*N_SEQ + ch*1024;
  f32x4 kvacc = (f32x4){0.f,0.f,0.f,0.f};
  float ksump[4] = {0.f,0.f,0.f,0.f};
  #pragma unroll 1
  for (int tile = 0; tile < 16; ++tile){
    const float* sp = src + tile*64;
    #pragma unroll
    for (int rr = 0; rr < 8; ++rr){        // coalesced along n; packed u32 LDS writes
      int c = w*16 + rr*2;
      float f0 = sp[(size_t)c*N_SEQ + lane];
      float f1 = sp[(size_t)(c+1)*N_SEQ + lane];
      *reinterpret_cast<u32*>(&Xl[xidx(lane, c)]) = pk2(f0, f1);
    }
    __syncthreads();
    f32x4 kh[4], vv[4];
    #pragma unroll
    for (int nt = 0; nt < 4; ++nt){ kh[nt] = (f32x4){0.f,0.f,0.f,0.f}; vv[nt] = kh[nt]; }
    gemmW(wkb, rb + m, 128, 0, Xl, m, g, kh);
    gemmW(wvb, rb + m, 128, 0, Xl, m, g, vv);
    #pragma unroll
    for (int nt = 0; nt < 4; ++nt)
      #pragma unroll
      for (int r = 0; r < 4; ++r){
        float x = fmaxf(kh[nt][r], 0.f) + EPSF;   // kh = relu(.)+eps
        ksump[r] += x;
        khl[kidx(rb + 4*g + r, nt*16 + m)] = f2b(x);
        vl [kidx(rb + 4*g + r, nt*16 + m)] = f2b(vv[nt][r]);
      }
    __syncthreads();
    // KV_w += kh_w(16 x 64n) @ v_w^T : A[d][k=n], B[k=n][col=m-feat]
    #pragma unroll
    for (int ks2 = 0; ks2 < 2; ++ks2){
      const bf16x8 av = *reinterpret_cast<const bf16x8*>(&khl[kidx(rb+m, ks2*32 + g*8)]);
      const bf16x8 bv = *reinterpret_cast<const bf16x8*>(&vl [kidx(rb+m, ks2*32 + g*8)]);
      kvacc = MFMA(av, bv, kvacc);
    }
  }
  size_t pb = (((size_t)(ch*4 + s)*8 + b)*8 + w)*256;
  #pragma unroll
  for (int r = 0; r < 4; ++r)
    pkv[pb + (size_t)(4*g + r)*16 + m] = kvacc[r];
  #pragma unroll
  for (int r = 0; r < 4; ++r){
    float v2 = ksump[r];
    v2 += __shfl_xor(v2, 1); v2 += __shfl_xor(v2, 2);
    v2 += __shfl_xor(v2, 4); v2 += __shfl_xor(v2, 8);
    if (m == 0) pks[(((size_t)(ch*4 + s)*8 + b)*8 + w)*16 + 4*g + r] = v2;
  }
}

// ---------------- Reduce partials; emit KV as prepacked bf16 A-fragments ---------------------------
__global__ void k_reduce(const float* __restrict__ pkv, const float* __restrict__ pks,
                         u32* __restrict__ kvb, float* __restrict__ ksf){
  int i = blockIdx.x*256 + threadIdx.x;   // grid 144*256 = 36864
  if (i < 32768){
    int sA = i >> 7, r7 = i & 127;
    int gb = r7 >> 6, m = (r7 >> 2) & 15, t = r7 & 3;
    int d = gb*8 + 2*t;
    float a0 = 0.f, a1 = 0.f;
    #pragma unroll
    for (int ch = 0; ch < 16; ++ch){
      a0 += pkv[(size_t)ch*65536 + sA*256 + d*16 + m];
      a1 += pkv[(size_t)ch*65536 + sA*256 + (d+1)*16 + m];
    }
    kvb[i] = pk2(a0, a1);
  } else {
    int j = i - 32768;   // < 4096
    float a = 0.f;
    #pragma unroll
    for (int ch = 0; ch < 16; ++ch) a += pks[(size_t)ch*4096 + j];
    ksf[j] = a;
  }
}

// ---------------- Pass 2: fused per-n pipeline, all GEMMs on MFMA ----------------------------------
__global__ __launch_bounds__(512, 4) void k_pass2(const float* __restrict__ t1,
    const float* __restrict__ t2, const float* __restrict__ t3, const float* __restrict__ fs,
    const u16* __restrict__ wqb, const u16* __restrict__ wbb, const u16* __restrict__ wob,
    const u32* __restrict__ kvb, const float* __restrict__ ksf, float* __restrict__ outp){
  __shared__ u16 Xl[64*128];       // 16384 B
  __shared__ u16 Ul[64*128];       // 16384 B
  __shared__ u16 Qt[8*64*QTS];     // 24576 B -> total 57344 B
  int bid = blockIdx.x;
  int b = bid >> 8, n0 = (bid & 255) * 64;
  int tid = threadIdx.x, lane = tid & 63;
  int w = rfl(tid >> 6), rb = w*16;
  int g = lane >> 4, m = lane & 15;
  f32x4 oacc[4];
  #pragma unroll
  for (int nt = 0; nt < 4; ++nt) oacc[nt] = (f32x4){0.f,0.f,0.f,0.f};

  #pragma unroll 1
  for (int i = 0; i < 3; ++i){
    const float* src = (i==0)?t1:(i==1)?t2:t3;
    int s1 = (i==0)?1:0, s2 = (i==2)?1:2;
    #pragma unroll
    for (int nt = 0; nt < 4; ++nt){
      float f0 = src[(size_t)(b*128 + rb + 4*g + 0)*N_SEQ + n0 + nt*16 + m];
      float f1 = src[(size_t)(b*128 + rb + 4*g + 1)*N_SEQ + n0 + nt*16 + m];
      float f2 = src[(size_t)(b*128 + rb + 4*g + 2)*N_SEQ + n0 + nt*16 + m];
      float f3 = src[(size_t)(b*128 + rb + 4*g + 3)*N_SEQ + n0 + nt*16 + m];
      *reinterpret_cast<uint2*>(&Xl[xidx(nt*16+m, rb + 4*g)]) =
        make_uint2(pk2(f0, f1), pk2(f2, f3));
    }
    __syncthreads();
    stage<2>(Xl, Ul, Qt, wqb, wbb, kvb, ksf, s1, s2, b, w, g, m, rb);  // stage A
    stage<1>(Xl, Ul, Qt, wqb, wbb, kvb, ksf, 3, 3, b, w, g, m, rb);    // stage B
    // acc += Wout[:, i*128 : i*128+128] @ t_if
    gemmW(wob, rb + m, 384, i*128, Xl, m, g, oacc);
    __syncthreads();   // before next i overwrites Xl
  }
  #pragma unroll
  for (int nt = 0; nt < 4; ++nt)
    #pragma unroll
    for (int r = 0; r < 4; ++r){
      size_t idx = (size_t)(b*128 + rb + 4*g + r)*N_SEQ + n0 + nt*16 + m;
      outp[idx] = oacc[nt][r] + fs[idx];
    }
}

extern "C" void kernel_launch(void* const* d_in, const int* in_sizes, int n_in,
                              void* d_out, int out_size, void* d_ws, size_t ws_size,
                              hipStream_t stream){
  const float* t1 = (const float*)d_in[0];
  const float* t2 = (const float*)d_in[1];
  const float* t3 = (const float*)d_in[2];
  const float* fs = (const float*)d_in[3];
  const float* Wq = (const float*)d_in[4];
  const float* Wk = (const float*)d_in[5];
  const float* Wv = (const float*)d_in[6];
  const float* Wb = (const float*)d_in[7];
  const float* Wo = (const float*)d_in[8];
  float* outp = (float*)d_out;
  float* ws = (float*)d_ws;
  // ws layout (float units):
  //   pkv [16*65536] | pks [16*4096] | ksf [4096] | kvb [32768 u32]
  //   | wqb,wkb,wvb,wbb [4 * 8192] | wob [24576]     (bf16 halves in float-sized slots)
  float* pkv = ws;
  float* pks = ws + 16*65536;
  float* ksf = ws + 16*65536 + 16*4096;
  u32*  kvb  = (u32*)(ksf + 4096);
  u16*  wqb  = (u16*)(kvb + 32768);
  u16*  wkb  = wqb + 16384;
  u16*  wvb  = wkb + 16384;
  u16*  wbb  = wvb + 16384;
  u16*  wob  = wbb + 16384;   // 49152 u16

  k_prepack<<<dim3(448),  dim3(256), 0, stream>>>(Wq, Wk, Wv, Wb, Wo, wqb, wkb, wvb, wbb, wob);
  k_pass1  <<<dim3(512),  dim3(512), 0, stream>>>(t1, t2, t3, fs, wkb, wvb, pkv, pks);
  k_reduce <<<dim3(144),  dim3(256), 0, stream>>>(pkv, pks, kvb, ksf);
  k_pass2  <<<dim3(2048), dim3(512), 0, stream>>>(t1, t2, t3, fs, wqb, wbb, wob, kvb, ksf, outp);
}